// Round 1
// baseline (151.251 us; speedup 1.0000x reference)
//
#include <hip/hip_runtime.h>
#include <math.h>

#define HW 56
#define PPI (HW*HW)          // 3136 pixels per image
#define NB 4
#define C 128
#define NPIX (NB*PPI)        // 12544
#define PAD 129

// ---------------- Kernel 1: conv3x3 stride2 pad1 + bias + relu, NCHW in -> NHWC out ----
__global__ __launch_bounds__(256) void conv_relu_kernel(
    const float* __restrict__ x, const float* __restrict__ cw,
    const float* __restrict__ cb, float* __restrict__ f)
{
    int idx = blockIdx.x * 256 + threadIdx.x;   // 12544*128 = 3,211,264/2 .. exact 1,605,632
    int c   = idx & 127;
    int pix = idx >> 7;
    int w   = pix % HW;
    int t2  = pix / HW;
    int h   = t2 % HW;
    int b   = t2 / HW;

    float acc = cb[c];
    const float* wb = cw + c * 27;
    #pragma unroll
    for (int ci = 0; ci < 3; ++ci) {
        const float* xb = x + ((size_t)(b*3 + ci) * 112) * 112;
        #pragma unroll
        for (int kh = 0; kh < 3; ++kh) {
            int ih = 2*h - 1 + kh;
            if (ih < 0 || ih >= 112) continue;
            #pragma unroll
            for (int kw = 0; kw < 3; ++kw) {
                int iw = 2*w - 1 + kw;
                if (iw < 0 || iw >= 112) continue;
                acc += xb[ih*112 + iw] * wb[(ci*3 + kh)*3 + kw];
            }
        }
    }
    f[idx] = fmaxf(acc, 0.0f);
}

// ---------------- Kernel 2: QKV GEMM (f [12544x128] @ W^T [128x128] + b) ---------------
// grid.x = 392 (32 pixels each), grid.y = 6 (3 matrices x 2 col-halves of 64)
__global__ __launch_bounds__(256) void qkv_kernel(
    const float* __restrict__ f,
    const float* __restrict__ qw, const float* __restrict__ qb,
    const float* __restrict__ kw, const float* __restrict__ kb,
    const float* __restrict__ vw, const float* __restrict__ vb,
    float* __restrict__ qo, float* __restrict__ ko, float* __restrict__ vo)
{
    __shared__ float fs[32 * PAD];
    __shared__ float wsl[64 * PAD];

    int t    = threadIdx.x;
    int pix0 = blockIdx.x * 32;
    int ysel = blockIdx.y;
    int mat  = ysel >> 1;
    int col0 = (ysel & 1) * 64;

    const float* W  = (mat == 0) ? qw : (mat == 1) ? kw : vw;
    const float* Bv = (mat == 0) ? qb : (mat == 1) ? kb : vb;
    float*       O  = (mat == 0) ? qo : (mat == 1) ? ko : vo;

    // stage f tile: 32x128 floats (4 float4 per thread), coalesced
    #pragma unroll
    for (int j = 0; j < 4; ++j) {
        int f4   = t + 256*j;
        int flat = f4 * 4;
        int p    = flat >> 7;
        int kk   = flat & 127;
        float4 vv = *reinterpret_cast<const float4*>(f + (size_t)(pix0 + p)*C + kk);
        fs[p*PAD + kk + 0] = vv.x; fs[p*PAD + kk + 1] = vv.y;
        fs[p*PAD + kk + 2] = vv.z; fs[p*PAD + kk + 3] = vv.w;
    }
    // stage W tile: 64x128 floats (8 float4 per thread)
    #pragma unroll
    for (int j = 0; j < 8; ++j) {
        int f4   = t + 256*j;
        int flat = f4 * 4;
        int r    = flat >> 7;
        int kk   = flat & 127;
        float4 vv = *reinterpret_cast<const float4*>(W + (size_t)(col0 + r)*C + kk);
        wsl[r*PAD + kk + 0] = vv.x; wsl[r*PAD + kk + 1] = vv.y;
        wsl[r*PAD + kk + 2] = vv.z; wsl[r*PAD + kk + 3] = vv.w;
    }
    __syncthreads();

    int c0 = t & 31;          // cols {c0, c0+32} of this 64-col tile
    int p0 = (t >> 5) * 4;    // pixels {p0..p0+3}
    float acc[4][2] = {{0.f,0.f},{0.f,0.f},{0.f,0.f},{0.f,0.f}};

    #pragma unroll 8
    for (int kk = 0; kk < C; ++kk) {
        float w0 = wsl[c0*PAD + kk];
        float w1 = wsl[(c0+32)*PAD + kk];
        #pragma unroll
        for (int i = 0; i < 4; ++i) {
            float fv = fs[(p0+i)*PAD + kk];
            acc[i][0] = fmaf(fv, w0, acc[i][0]);
            acc[i][1] = fmaf(fv, w1, acc[i][1]);
        }
    }

    float b0 = Bv[col0 + c0];
    float b1 = Bv[col0 + c0 + 32];
    #pragma unroll
    for (int i = 0; i < 4; ++i) {
        size_t row = (size_t)(pix0 + p0 + i) * C;
        O[row + col0 + c0]      = acc[i][0] + b0;
        O[row + col0 + c0 + 32] = acc[i][1] + b1;
    }
}

// ---------------- Kernel 3: 7x7 neighborhood attention, one wave per pixel -------------
__global__ __launch_bounds__(256) void attn_kernel(
    const float* __restrict__ q, const float* __restrict__ k,
    const float* __restrict__ v, float* __restrict__ out)
{
    __shared__ __align__(16) float q_s[4][C];
    __shared__ float a_s[4][64];
    __shared__ int   n_s[4][64];

    int wid  = threadIdx.x >> 6;
    int lane = threadIdx.x & 63;
    int pix  = blockIdx.x * 4 + wid;       // 3136 blocks * 4 = 12544
    int b    = pix / PPI;
    int rem  = pix % PPI;
    int h    = rem / HW;
    int w    = rem % HW;

    q_s[wid][lane]      = q[(size_t)pix*C + lane];
    q_s[wid][lane + 64] = q[(size_t)pix*C + 64 + lane];

    int hs = min(max(h - 3, 0), HW - 7);
    int ws_ = min(max(w - 3, 0), HW - 7);
    if (lane < 49) {
        int ih = hs + lane / 7;
        int iw = ws_ + lane % 7;
        n_s[wid][lane] = (b*PPI + ih*HW + iw) * C;
    }
    __syncthreads();

    const float scale = 0.08838834764831845f;   // 128^-0.5
    float logit = -INFINITY;
    if (lane < 49) {
        const float* kb = k + n_s[wid][lane];
        float acc = 0.f;
        #pragma unroll
        for (int c = 0; c < C; c += 4) {
            float4 kv = *reinterpret_cast<const float4*>(kb + c);
            float4 qv = *reinterpret_cast<const float4*>(&q_s[wid][c]);
            acc = fmaf(qv.x, kv.x, acc);
            acc = fmaf(qv.y, kv.y, acc);
            acc = fmaf(qv.z, kv.z, acc);
            acc = fmaf(qv.w, kv.w, acc);
        }
        logit = acc * scale;
    }

    // wave-wide softmax over 49 valid lanes
    float m = logit;
    #pragma unroll
    for (int d = 1; d < 64; d <<= 1) m = fmaxf(m, __shfl_xor(m, d));
    float e = (lane < 49) ? __expf(logit - m) : 0.f;
    float s = e;
    #pragma unroll
    for (int d = 1; d < 64; d <<= 1) s += __shfl_xor(s, d);
    a_s[wid][lane] = (lane < 49) ? (e / s) : 0.f;
    __syncthreads();

    float acc0 = 0.f, acc1 = 0.f;
    #pragma unroll 7
    for (int ij = 0; ij < 49; ++ij) {
        float a = a_s[wid][ij];
        const float* vb = v + n_s[wid][ij];
        acc0 = fmaf(a, vb[lane],      acc0);
        acc1 = fmaf(a, vb[64 + lane], acc1);
    }

    // out is NCHW: ((b*128 + c)*56 + h)*56 + w
    size_t ob = (size_t)b * C * PPI + (size_t)h * HW + w;
    out[ob + (size_t)lane * PPI]        = acc0;
    out[ob + (size_t)(lane + 64) * PPI] = acc1;
}

extern "C" void kernel_launch(void* const* d_in, const int* in_sizes, int n_in,
                              void* d_out, int out_size, void* d_ws, size_t ws_size,
                              hipStream_t stream) {
    const float* x      = (const float*)d_in[0];
    const float* conv_w = (const float*)d_in[1];
    const float* conv_b = (const float*)d_in[2];
    const float* q_w    = (const float*)d_in[3];
    const float* q_b    = (const float*)d_in[4];
    const float* k_w    = (const float*)d_in[5];
    const float* k_b    = (const float*)d_in[6];
    const float* v_w    = (const float*)d_in[7];
    const float* v_b    = (const float*)d_in[8];
    float* out = (float*)d_out;

    float* f  = (float*)d_ws;
    float* qo = f  + (size_t)NPIX * C;
    float* ko = qo + (size_t)NPIX * C;
    float* vo = ko + (size_t)NPIX * C;

    conv_relu_kernel<<<NPIX*C/256, 256, 0, stream>>>(x, conv_w, conv_b, f);
    qkv_kernel<<<dim3(NPIX/32, 6), 256, 0, stream>>>(f, q_w, q_b, k_w, k_b, v_w, v_b,
                                                     qo, ko, vo);
    attn_kernel<<<NPIX/4, 256, 0, stream>>>(qo, ko, vo, out);
}

// Round 2
// 86.490 us; speedup vs baseline: 1.7488x; 1.7488x over previous
//
#include <hip/hip_runtime.h>
#include <hip/hip_bf16.h>
#include <math.h>

#define HW 56
#define PPI (HW*HW)          // 3136 pixels per image
#define NB 4
#define C 128
#define NPIX (NB*PPI)        // 12544
#define CONV_BLOCKS (NPIX*C/256)   // 6272
#define WPREP_BLOCKS 192           // 3*128*128/256

typedef __attribute__((ext_vector_type(8))) short short8;
typedef __attribute__((ext_vector_type(4))) float f32x4;

__device__ __forceinline__ float bflo(unsigned v){
    union { unsigned u; float f; } x; x.u = v << 16; return x.f;
}
__device__ __forceinline__ float bfhi(unsigned v){
    union { unsigned u; float f; } x; x.u = v & 0xFFFF0000u; return x.f;
}

// ---------- Kernel 1: conv3x3 s2 p1 + bias + relu -> bf16 NHWC  (+ W bf16 frag prep) ----
__global__ __launch_bounds__(256) void conv_wprep_kernel(
    const float* __restrict__ x, const float* __restrict__ cw,
    const float* __restrict__ cb,
    const float* __restrict__ qw, const float* __restrict__ kw,
    const float* __restrict__ vw,
    __hip_bfloat16* __restrict__ f, __hip_bfloat16* __restrict__ wfrag)
{
    if (blockIdx.x >= CONV_BLOCKS) {
        // convert q_w/k_w/v_w (f32 [128][128], row=outcol, col=k) to bf16 fragment layout:
        // offset(m, col, k) = m*16384 + ((kk*4+hi)*128 + col)*8 + j, kk=k>>5, hi=(k>>3)&3, j=k&7
        int idx = (blockIdx.x - CONV_BLOCKS) * 256 + threadIdx.x;   // 0..49151
        int m   = idx >> 14;
        int r   = idx & 16383;
        int col = r >> 7;
        int k   = r & 127;
        const float* W = (m == 0) ? qw : (m == 1) ? kw : vw;
        float val = W[col * 128 + k];
        int kk = k >> 5, hi = (k >> 3) & 3, j = k & 7;
        wfrag[m * 16384 + ((kk * 4 + hi) * 128 + col) * 8 + j] = __float2bfloat16(val);
        return;
    }

    int idx = blockIdx.x * 256 + threadIdx.x;
    int c   = idx & 127;
    int pix = idx >> 7;
    int w   = pix % HW;
    int t2  = pix / HW;
    int h   = t2 % HW;
    int b   = t2 / HW;

    float acc = cb[c];
    const float* wb = cw + c * 27;
    #pragma unroll
    for (int ci = 0; ci < 3; ++ci) {
        const float* xb = x + ((size_t)(b*3 + ci) * 112) * 112;
        #pragma unroll
        for (int kh = 0; kh < 3; ++kh) {
            int ih = 2*h - 1 + kh;
            if (ih < 0 || ih >= 112) continue;
            #pragma unroll
            for (int kw_ = 0; kw_ < 3; ++kw_) {
                int iw = 2*w - 1 + kw_;
                if (iw < 0 || iw >= 112) continue;
                acc += xb[ih*112 + iw] * wb[(ci*3 + kh)*3 + kw_];
            }
        }
    }
    f[idx] = __float2bfloat16(fmaxf(acc, 0.0f));
}

// ---------- Kernel 2: QKV GEMM via MFMA bf16, no LDS ----------------------------------
// grid (NPIX/64, 3); block 256 = 4 waves; wave does 16 pixels x 128 cols.
__global__ __launch_bounds__(256) void qkv_mfma_kernel(
    const __hip_bfloat16* __restrict__ f, const __hip_bfloat16* __restrict__ wfrag,
    const float* __restrict__ qb, const float* __restrict__ kb, const float* __restrict__ vb,
    __hip_bfloat16* __restrict__ qo, __hip_bfloat16* __restrict__ ko,
    __hip_bfloat16* __restrict__ vo)
{
    int lane = threadIdx.x & 63, wid = threadIdx.x >> 6;
    int mat  = blockIdx.y;
    const float* Bv      = (mat == 0) ? qb : (mat == 1) ? kb : vb;
    __hip_bfloat16* O    = (mat == 0) ? qo : (mat == 1) ? ko : vo;

    int r16 = lane & 15, hi = lane >> 4;
    int pixr = blockIdx.x * 64 + wid * 16 + r16;

    // A fragments: k = kk*32 + hi*8 + j (row = r16)
    const __hip_bfloat16* fp = f + (size_t)pixr * C + hi * 8;
    short8 a0 = *(const short8*)(fp);
    short8 a1 = *(const short8*)(fp + 32);
    short8 a2 = *(const short8*)(fp + 64);
    short8 a3 = *(const short8*)(fp + 96);

    // B fragments (pre-arranged): base + kk*4096 + hi*1024 + col*8
    const __hip_bfloat16* wbase = wfrag + mat * 16384 + hi * 1024 + r16 * 8;
    int orow = blockIdx.x * 64 + wid * 16 + hi * 4;

    #pragma unroll
    for (int nt = 0; nt < 8; ++nt) {
        f32x4 acc = {0.f, 0.f, 0.f, 0.f};
        acc = __builtin_amdgcn_mfma_f32_16x16x32_bf16(a0, *(const short8*)(wbase + nt*128 +     0), acc, 0, 0, 0);
        acc = __builtin_amdgcn_mfma_f32_16x16x32_bf16(a1, *(const short8*)(wbase + nt*128 +  4096), acc, 0, 0, 0);
        acc = __builtin_amdgcn_mfma_f32_16x16x32_bf16(a2, *(const short8*)(wbase + nt*128 +  8192), acc, 0, 0, 0);
        acc = __builtin_amdgcn_mfma_f32_16x16x32_bf16(a3, *(const short8*)(wbase + nt*128 + 12288), acc, 0, 0, 0);
        int col  = nt * 16 + r16;
        float bb = Bv[col];
        #pragma unroll
        for (int rg = 0; rg < 4; ++rg)
            O[(size_t)(orow + rg) * C + col] = __float2bfloat16(acc[rg] + bb);
    }
}

// ---------- Kernel 3: 7x7 neighborhood attention, LDS-tiled (4x4 pixel tile/block) -----
__global__ __launch_bounds__(256) void attn_kernel(
    const __hip_bfloat16* __restrict__ qg, const __hip_bfloat16* __restrict__ kg,
    const __hip_bfloat16* __restrict__ vg, float* __restrict__ out)
{
    __shared__ unsigned kT[64 * 113];    // [c2][col] transposed bf16-pairs, pad 113
    __shared__ unsigned v_su[100 * 64];  // [col][c2] row-major bf16-pairs
    __shared__ unsigned q_su[16 * 64];   // [pix][c2]
    __shared__ uint2    ac_s[4][64];     // per-wave (attn weight, col)

    int t  = threadIdx.x;
    int bx = blockIdx.x;                 // 4 * 14 * 14 = 784
    int b  = bx / 196;
    int rr = bx % 196;
    int th = rr / 14, tw = rr % 14;
    int ih0 = min(max(th*4 - 3, 0), HW - 10);
    int iw0 = min(max(tw*4 - 3, 0), HW - 10);

    const unsigned* kgu = (const unsigned*)kg;
    const unsigned* vgu = (const unsigned*)vg;
    const unsigned* qgu = (const unsigned*)qg;

    // stage k (transposed) + v (row-major): 100 rows x 64 c-pairs
    for (int i = t; i < 6400; i += 256) {
        int col = i >> 6, c2 = i & 63;
        int pix = b*PPI + (ih0 + col/10)*HW + (iw0 + col%10);
        unsigned kvv = kgu[(size_t)pix*64 + c2];
        unsigned vvv = vgu[(size_t)pix*64 + c2];
        kT[c2*113 + col]  = kvv;
        v_su[col*64 + c2] = vvv;
    }
    // stage q: 16 tile pixels x 64 c-pairs
    for (int i = t; i < 1024; i += 256) {
        int p = i >> 6, c2 = i & 63;
        int h = th*4 + (p >> 2), w = tw*4 + (p & 3);
        q_su[i] = qgu[(size_t)(b*PPI + h*HW + w)*64 + c2];
    }
    __syncthreads();

    int lane = t & 63, wid = t >> 6;
    int r7 = lane / 7, s7 = lane - 7*r7;
    bool valid = lane < 49;
    const float scale = 0.08838834764831845f;   // 128^-0.5

    #pragma unroll
    for (int px = 0; px < 4; ++px) {
        int p = wid*4 + px;
        int h = th*4 + (p >> 2), w = tw*4 + (p & 3);
        int hs = min(max(h - 3, 0), HW - 7);
        int ws = min(max(w - 3, 0), HW - 7);
        int col = (hs - ih0 + r7)*10 + (ws - iw0 + s7);
        if (!valid) col = 0;

        // QK: lane = neighbor, loop over channel pairs
        float acc = 0.f;
        #pragma unroll 8
        for (int c2 = 0; c2 < 64; ++c2) {
            unsigned kv = kT[c2*113 + col];
            unsigned qv = q_su[p*64 + c2];
            acc = fmaf(bflo(qv), bflo(kv), acc);
            acc = fmaf(bfhi(qv), bfhi(kv), acc);
        }
        float logit = valid ? acc * scale : -INFINITY;

        // wave softmax over 49 valid lanes
        float m = logit;
        #pragma unroll
        for (int d = 1; d < 64; d <<= 1) m = fmaxf(m, __shfl_xor(m, d));
        float e = valid ? __expf(logit - m) : 0.f;
        float s = e;
        #pragma unroll
        for (int d = 1; d < 64; d <<= 1) s += __shfl_xor(s, d);
        float a = e / s;
        ac_s[wid][lane] = make_uint2(__float_as_uint(a), (unsigned)col);

        // PV: lane = channel pair, loop over 49 neighbors
        float o0 = 0.f, o1 = 0.f;
        #pragma unroll
        for (int n = 0; n < 49; ++n) {
            uint2 ac = ac_s[wid][n];
            unsigned vv = v_su[ac.y*64 + lane];
            float av = __uint_as_float(ac.x);
            o0 = fmaf(av, bflo(vv), o0);
            o1 = fmaf(av, bfhi(vv), o1);
        }

        // out NCHW
        size_t ob = (size_t)b * C * PPI + (size_t)h * HW + w;
        out[ob + (size_t)(2*lane)     * PPI] = o0;
        out[ob + (size_t)(2*lane + 1) * PPI] = o1;
    }
}

extern "C" void kernel_launch(void* const* d_in, const int* in_sizes, int n_in,
                              void* d_out, int out_size, void* d_ws, size_t ws_size,
                              hipStream_t stream) {
    const float* x      = (const float*)d_in[0];
    const float* conv_w = (const float*)d_in[1];
    const float* conv_b = (const float*)d_in[2];
    const float* q_w    = (const float*)d_in[3];
    const float* q_b    = (const float*)d_in[4];
    const float* k_w    = (const float*)d_in[5];
    const float* k_b    = (const float*)d_in[6];
    const float* v_w    = (const float*)d_in[7];
    const float* v_b    = (const float*)d_in[8];
    float* out = (float*)d_out;

    __hip_bfloat16* f_bf  = (__hip_bfloat16*)d_ws;       // NPIX*C
    __hip_bfloat16* q_bf  = f_bf + (size_t)NPIX * C;
    __hip_bfloat16* k_bf  = q_bf + (size_t)NPIX * C;
    __hip_bfloat16* v_bf  = k_bf + (size_t)NPIX * C;
    __hip_bfloat16* wfrag = v_bf + (size_t)NPIX * C;     // 3*16384

    conv_wprep_kernel<<<CONV_BLOCKS + WPREP_BLOCKS, 256, 0, stream>>>(
        x, conv_w, conv_b, q_w, k_w, v_w, f_bf, wfrag);
    qkv_mfma_kernel<<<dim3(NPIX/64, 3), 256, 0, stream>>>(
        f_bf, wfrag, q_b, k_b, v_b, q_bf, k_bf, v_bf);
    attn_kernel<<<NB*14*14, 256, 0, stream>>>(q_bf, k_bf, v_bf, out);
}

// Round 3
// 70.649 us; speedup vs baseline: 2.1409x; 1.2242x over previous
//
#include <hip/hip_runtime.h>
#include <hip/hip_bf16.h>
#include <math.h>

#define HW 56
#define PPI (HW*HW)          // 3136 pixels per image
#define NB 4
#define C 128
#define NPIX (NB*PPI)        // 12544
#define CONV_BLOCKS (NPIX*C/256)   // 6272
#define WPREP_BLOCKS 192           // 3*128*128/256

typedef __attribute__((ext_vector_type(8))) short short8;
typedef __attribute__((ext_vector_type(4))) float f32x4;

// ---------- Kernel 1: conv3x3 s2 p1 + bias + relu -> bf16 NHWC  (+ W bf16 frag prep) ----
__global__ __launch_bounds__(256) void conv_wprep_kernel(
    const float* __restrict__ x, const float* __restrict__ cw,
    const float* __restrict__ cb,
    const float* __restrict__ qw, const float* __restrict__ kw,
    const float* __restrict__ vw,
    __hip_bfloat16* __restrict__ f, __hip_bfloat16* __restrict__ wfrag)
{
    if (blockIdx.x >= CONV_BLOCKS) {
        // W (f32 [128 outcol][128 k]) -> bf16 MFMA-B fragment layout:
        // offset(m, col, k) = m*16384 + ((kk*4+hi)*128 + col)*8 + j ; kk=k>>5, hi=(k>>3)&3, j=k&7
        int idx = (blockIdx.x - CONV_BLOCKS) * 256 + threadIdx.x;   // 0..49151
        int m   = idx >> 14;
        int r   = idx & 16383;
        int col = r >> 7;
        int k   = r & 127;
        const float* W = (m == 0) ? qw : (m == 1) ? kw : vw;
        float val = W[col * 128 + k];
        int kk = k >> 5, hi = (k >> 3) & 3, j = k & 7;
        wfrag[m * 16384 + ((kk * 4 + hi) * 128 + col) * 8 + j] = __float2bfloat16(val);
        return;
    }

    int idx = blockIdx.x * 256 + threadIdx.x;
    int c   = idx & 127;
    int pix = idx >> 7;
    int w   = pix % HW;
    int t2  = pix / HW;
    int h   = t2 % HW;
    int b   = t2 / HW;

    float acc = cb[c];
    const float* wb = cw + c * 27;
    #pragma unroll
    for (int ci = 0; ci < 3; ++ci) {
        const float* xb = x + ((size_t)(b*3 + ci) * 112) * 112;
        #pragma unroll
        for (int kh = 0; kh < 3; ++kh) {
            int ih = 2*h - 1 + kh;
            if (ih < 0 || ih >= 112) continue;
            #pragma unroll
            for (int kw_ = 0; kw_ < 3; ++kw_) {
                int iw = 2*w - 1 + kw_;
                if (iw < 0 || iw >= 112) continue;
                acc += xb[ih*112 + iw] * wb[(ci*3 + kh)*3 + kw_];
            }
        }
    }
    f[idx] = __float2bfloat16(fmaxf(acc, 0.0f));
}

// ---------- Kernel 2: QKV GEMM via MFMA bf16, no LDS ----------------------------------
// grid (NPIX/64, 3, 2); block 256 = 4 waves; wave does 16 pixels x 64 cols.
__global__ __launch_bounds__(256) void qkv_mfma_kernel(
    const __hip_bfloat16* __restrict__ f, const __hip_bfloat16* __restrict__ wfrag,
    const float* __restrict__ qb, const float* __restrict__ kb, const float* __restrict__ vb,
    __hip_bfloat16* __restrict__ qo, __hip_bfloat16* __restrict__ ko,
    __hip_bfloat16* __restrict__ vo)
{
    int lane = threadIdx.x & 63, wid = threadIdx.x >> 6;
    int mat  = blockIdx.y;
    int z    = blockIdx.z;
    const float* Bv      = (mat == 0) ? qb : (mat == 1) ? kb : vb;
    __hip_bfloat16* O    = (mat == 0) ? qo : (mat == 1) ? ko : vo;

    int r16 = lane & 15, hi = lane >> 4;
    int pixr = blockIdx.x * 64 + wid * 16 + r16;

    // A fragments: row=r16 (pixel), k = kk*32 + hi*8 + j
    const __hip_bfloat16* fp = f + (size_t)pixr * C + hi * 8;
    short8 a0 = *(const short8*)(fp);
    short8 a1 = *(const short8*)(fp + 32);
    short8 a2 = *(const short8*)(fp + 64);
    short8 a3 = *(const short8*)(fp + 96);

    const __hip_bfloat16* wbase = wfrag + mat * 16384 + hi * 1024 + r16 * 8;
    int orow = blockIdx.x * 64 + wid * 16 + hi * 4;

    #pragma unroll
    for (int ntl = 0; ntl < 4; ++ntl) {
        int nt = z * 4 + ntl;
        f32x4 acc = {0.f, 0.f, 0.f, 0.f};
        acc = __builtin_amdgcn_mfma_f32_16x16x32_bf16(a0, *(const short8*)(wbase + nt*128 +     0), acc, 0, 0, 0);
        acc = __builtin_amdgcn_mfma_f32_16x16x32_bf16(a1, *(const short8*)(wbase + nt*128 +  4096), acc, 0, 0, 0);
        acc = __builtin_amdgcn_mfma_f32_16x16x32_bf16(a2, *(const short8*)(wbase + nt*128 +  8192), acc, 0, 0, 0);
        acc = __builtin_amdgcn_mfma_f32_16x16x32_bf16(a3, *(const short8*)(wbase + nt*128 + 12288), acc, 0, 0, 0);
        int col  = nt * 16 + r16;
        float bb = Bv[col];
        #pragma unroll
        for (int rg = 0; rg < 4; ++rg)
            O[(size_t)(orow + rg) * C + col] = __float2bfloat16(acc[rg] + bb);
    }
}

// ---------- Kernel 3: 7x7 NAT via MFMA, 4x4 pixel tile per block -----------------------
// logits[16 px][112 nbr] = MFMA(Q-frags from global, K-frags from global)
// softmax: 1 LDS read + 1 bf16 scatter per (px,nbr)
// PV: MFMA(attnW from LDS, vT from LDS)
#define VPITCH 272   // bytes per vT / attnW row (136 shorts = 17*16B)

__global__ __launch_bounds__(256) void attn_kernel(
    const __hip_bfloat16* __restrict__ qg, const __hip_bfloat16* __restrict__ kg,
    const __hip_bfloat16* __restrict__ vg, float* __restrict__ out)
{
    __shared__ __align__(16) short vT[128 * 136];       // 34816 B: vT[c][n] (swizzled)
    __shared__ __align__(16) float logit_s[16 * 116];   //  7424 B
    __shared__ __align__(16) short attnW[16 * 136];     //  4352 B: attnW[p][n]

    int t    = threadIdx.x;
    int lane = t & 63, wid = t >> 6;
    int r16  = lane & 15, hi = lane >> 4;

    int bx = blockIdx.x;                 // 4 * 196
    int b  = bx / 196;
    int rr = bx % 196;
    int th = rr / 14, tw = rr % 14;
    int ih0 = min(max(th*4 - 3, 0), HW - 10);
    int iw0 = min(max(tw*4 - 3, 0), HW - 10);

    // zero attnW (read as A-operand with K=128; cols >= window must be 0)
    {
        unsigned* aw = (unsigned*)attnW;
        for (int i = t; i < 1088; i += 256) aw[i] = 0u;
    }

    // stage vT[c][n] = v[pix(n)][c], n packed in pairs (u32), rows c & c+1 per thread.
    // phys byte within row: (4*np) ^ (hsw<<4), hsw = (c>>3)&7  (XOR bits 4-6 only)
    const unsigned* vgu = (const unsigned*)vg;
    #pragma unroll 4
    for (int it = 0; it < 16; ++it) {
        int i  = t + 256*it;        // 0..4095
        int np = i >> 6;            // 0..63  (neighbor pair, covers n 0..127)
        int c2 = i & 63;
        int n0 = min(2*np,     99);
        int n1 = min(2*np + 1, 99);
        int p0 = b*PPI + (ih0 + n0/10)*HW + (iw0 + n0%10);
        int p1 = b*PPI + (ih0 + n1/10)*HW + (iw0 + n1%10);
        unsigned av = vgu[(size_t)p0*64 + c2];
        unsigned bv = vgu[(size_t)p1*64 + c2];
        unsigned w0 = (av & 0xffffu) | (bv << 16);          // channels 2c2 of n0,n1
        unsigned w1 = (av >> 16)     | (bv & 0xffff0000u);  // channels 2c2+1
        int c    = 2*c2;
        int hsw  = (c >> 3) & 7;
        int off  = (4*np) ^ (hsw << 4);
        *(unsigned*)((char*)vT + c*VPITCH + off)          = w0;
        *(unsigned*)((char*)vT + c*VPITCH + VPITCH + off) = w1;
    }

    // Q A-fragments (row = r16 = tile pixel), direct from global
    int ph = th*4 + (r16 >> 2), pw = tw*4 + (r16 & 3);
    const short* qrow = (const short*)qg + (size_t)(b*PPI + ph*HW + pw)*C + hi*8;
    short8 qa0 = *(const short8*)(qrow);
    short8 qa1 = *(const short8*)(qrow + 32);
    short8 qa2 = *(const short8*)(qrow + 64);
    short8 qa3 = *(const short8*)(qrow + 96);

    __syncthreads();

    // QK^T: logits[16][112], N-tiles split across waves
    for (int nt = wid; nt < 7; nt += 4) {
        int n  = nt*16 + r16;
        int nc = min(n, 99);
        int kp = b*PPI + (ih0 + nc/10)*HW + (iw0 + nc%10);
        const short* krow = (const short*)kg + (size_t)kp*C + hi*8;
        f32x4 acc = {0.f, 0.f, 0.f, 0.f};
        acc = __builtin_amdgcn_mfma_f32_16x16x32_bf16(qa0, *(const short8*)(krow),      acc, 0, 0, 0);
        acc = __builtin_amdgcn_mfma_f32_16x16x32_bf16(qa1, *(const short8*)(krow + 32), acc, 0, 0, 0);
        acc = __builtin_amdgcn_mfma_f32_16x16x32_bf16(qa2, *(const short8*)(krow + 64), acc, 0, 0, 0);
        acc = __builtin_amdgcn_mfma_f32_16x16x32_bf16(qa3, *(const short8*)(krow + 96), acc, 0, 0, 0);
        #pragma unroll
        for (int rg = 0; rg < 4; ++rg)
            logit_s[(hi*4 + rg)*116 + nt*16 + r16] = acc[rg];
    }
    __syncthreads();

    // softmax per pixel (4 px per wave), scatter bf16 weights into attnW
    {
        int r7 = lane / 7, s7 = lane - 7*r7;
        bool valid = lane < 49;
        const float scale = 0.08838834764831845f;   // 128^-0.5
        #pragma unroll
        for (int px = 0; px < 4; ++px) {
            int p = wid*4 + px;
            int h = th*4 + (p >> 2), w = tw*4 + (p & 3);
            int hs = min(max(h - 3, 0), HW - 7);
            int ws = min(max(w - 3, 0), HW - 7);
            int col = (hs - ih0 + r7)*10 + (ws - iw0 + s7);
            float lg = valid ? logit_s[p*116 + col] * scale : -INFINITY;
            float m = lg;
            #pragma unroll
            for (int d = 1; d < 64; d <<= 1) m = fmaxf(m, __shfl_xor(m, d));
            float e = valid ? __expf(lg - m) : 0.f;
            float s = e;
            #pragma unroll
            for (int d = 1; d < 64; d <<= 1) s += __shfl_xor(s, d);
            if (valid) {
                __hip_bfloat16 hb = __float2bfloat16(e / s);
                *(__hip_bfloat16*)((char*)attnW + p*VPITCH + 2*col) = hb;
            }
        }
    }
    __syncthreads();

    // PV: out[16][128] = attnW[16][128] x vT^T ; A from attnW rows, B from vT rows
    short8 pa[4];
    #pragma unroll
    for (int kk = 0; kk < 4; ++kk)
        pa[kk] = *(const short8*)((char*)attnW + r16*VPITCH + kk*64 + hi*16);

    for (int nt = wid; nt < 8; nt += 4) {
        int c   = nt*16 + r16;
        int hsw = (c >> 3) & 7;
        const char* vrow = (const char*)vT + c*VPITCH;
        f32x4 acc = {0.f, 0.f, 0.f, 0.f};
        #pragma unroll
        for (int kk = 0; kk < 4; ++kk) {
            short8 vb = *(const short8*)(vrow + ((kk*64 + hi*16) ^ (hsw << 4)));
            acc = __builtin_amdgcn_mfma_f32_16x16x32_bf16(pa[kk], vb, acc, 0, 0, 0);
        }
        #pragma unroll
        for (int rg = 0; rg < 4; ++rg) {
            int p = hi*4 + rg;
            int h = th*4 + (p >> 2), w = tw*4 + (p & 3);
            out[(((size_t)b*C + c)*HW + h)*HW + w] = acc[rg];
        }
    }
}

extern "C" void kernel_launch(void* const* d_in, const int* in_sizes, int n_in,
                              void* d_out, int out_size, void* d_ws, size_t ws_size,
                              hipStream_t stream) {
    const float* x      = (const float*)d_in[0];
    const float* conv_w = (const float*)d_in[1];
    const float* conv_b = (const float*)d_in[2];
    const float* q_w    = (const float*)d_in[3];
    const float* q_b    = (const float*)d_in[4];
    const float* k_w    = (const float*)d_in[5];
    const float* k_b    = (const float*)d_in[6];
    const float* v_w    = (const float*)d_in[7];
    const float* v_b    = (const float*)d_in[8];
    float* out = (float*)d_out;

    __hip_bfloat16* f_bf  = (__hip_bfloat16*)d_ws;       // NPIX*C
    __hip_bfloat16* q_bf  = f_bf + (size_t)NPIX * C;
    __hip_bfloat16* k_bf  = q_bf + (size_t)NPIX * C;
    __hip_bfloat16* v_bf  = k_bf + (size_t)NPIX * C;
    __hip_bfloat16* wfrag = v_bf + (size_t)NPIX * C;     // 3*16384

    conv_wprep_kernel<<<CONV_BLOCKS + WPREP_BLOCKS, 256, 0, stream>>>(
        x, conv_w, conv_b, q_w, k_w, v_w, f_bf, wfrag);
    qkv_mfma_kernel<<<dim3(NPIX/64, 3, 2), 256, 0, stream>>>(
        f_bf, wfrag, q_b, k_b, v_b, q_bf, k_bf, v_bf);
    attn_kernel<<<NB*14*14, 256, 0, stream>>>(q_bf, k_bf, v_bf, out);
}

// Round 4
// 55.775 us; speedup vs baseline: 2.7118x; 1.2667x over previous
//
#include <hip/hip_runtime.h>
#include <hip/hip_bf16.h>
#include <math.h>

#define HW 56
#define PPI (HW*HW)          // 3136 pixels per image
#define NB 4
#define C 128
#define NPIX (NB*PPI)        // 12544
#define CONV_BLOCKS2 (NPIX/8)      // 1568 (8 pixels x 128 ch per block)
#define WPREP_BLOCKS 192           // 3*128*128/256

typedef __attribute__((ext_vector_type(8))) short short8;
typedef __attribute__((ext_vector_type(4))) float f32x4;

// ---------- Kernel 1: conv3x3 s2 p1 + bias + relu -> bf16 NHWC  (+ W bf16 frag prep) ----
// Weights staged in LDS: lane=c gather is bank-conflict-free (stride 27 odd -> 2-way max).
__global__ __launch_bounds__(256) void conv_wprep_kernel(
    const float* __restrict__ x, const float* __restrict__ cw,
    const float* __restrict__ cb,
    const float* __restrict__ qw, const float* __restrict__ kw,
    const float* __restrict__ vw,
    __hip_bfloat16* __restrict__ f, __hip_bfloat16* __restrict__ wfrag)
{
    if (blockIdx.x >= CONV_BLOCKS2) {
        // W (f32 [128 outcol][128 k]) -> bf16 MFMA-B fragment layout:
        // offset(m, col, k) = m*16384 + ((kk*4+hi)*128 + col)*8 + j ; kk=k>>5, hi=(k>>3)&3, j=k&7
        int idx = (blockIdx.x - CONV_BLOCKS2) * 256 + threadIdx.x;   // 0..49151
        int m   = idx >> 14;
        int r   = idx & 16383;
        int col = r >> 7;
        int k   = r & 127;
        const float* W = (m == 0) ? qw : (m == 1) ? kw : vw;
        float val = W[col * 128 + k];
        int kk = k >> 5, hi = (k >> 3) & 3, j = k & 7;
        wfrag[m * 16384 + ((kk * 4 + hi) * 128 + col) * 8 + j] = __float2bfloat16(val);
        return;
    }

    __shared__ float wsm[128 * 27];   // 13824 B

    int t = threadIdx.x;
    for (int i = t; i < 3456; i += 256) wsm[i] = cw[i];
    __syncthreads();

    int c  = t & 127;
    int po = t >> 7;            // 0 or 1
    float bias = cb[c];
    const float* wb = &wsm[c * 27];

    #pragma unroll
    for (int it = 0; it < 4; ++it) {
        int pix = blockIdx.x * 8 + it * 2 + po;
        int w   = pix % HW;
        int t2  = pix / HW;
        int h   = t2 % HW;
        int b   = t2 / HW;

        float acc = bias;
        #pragma unroll
        for (int ci = 0; ci < 3; ++ci) {
            const float* xb = x + ((size_t)(b*3 + ci) * 112) * 112;
            #pragma unroll
            for (int kh = 0; kh < 3; ++kh) {
                int ih = 2*h - 1 + kh;
                if (ih < 0 || ih >= 112) continue;
                #pragma unroll
                for (int kw_ = 0; kw_ < 3; ++kw_) {
                    int iw = 2*w - 1 + kw_;
                    if (iw < 0 || iw >= 112) continue;
                    acc += xb[ih*112 + iw] * wb[(ci*3 + kh)*3 + kw_];
                }
            }
        }
        f[(size_t)pix * C + c] = __float2bfloat16(fmaxf(acc, 0.0f));
    }
}

// ---------- Kernel 2: QKV GEMM via MFMA bf16, no LDS ----------------------------------
// grid (NPIX/64, 3, 2); block 256 = 4 waves; wave does 16 pixels x 64 cols.
__global__ __launch_bounds__(256) void qkv_mfma_kernel(
    const __hip_bfloat16* __restrict__ f, const __hip_bfloat16* __restrict__ wfrag,
    const float* __restrict__ qb, const float* __restrict__ kb, const float* __restrict__ vb,
    __hip_bfloat16* __restrict__ qo, __hip_bfloat16* __restrict__ ko,
    __hip_bfloat16* __restrict__ vo)
{
    int lane = threadIdx.x & 63, wid = threadIdx.x >> 6;
    int mat  = blockIdx.y;
    int z    = blockIdx.z;
    const float* Bv      = (mat == 0) ? qb : (mat == 1) ? kb : vb;
    __hip_bfloat16* O    = (mat == 0) ? qo : (mat == 1) ? ko : vo;

    int r16 = lane & 15, hi = lane >> 4;
    int pixr = blockIdx.x * 64 + wid * 16 + r16;

    // A fragments: row=r16 (pixel), k = kk*32 + hi*8 + j
    const __hip_bfloat16* fp = f + (size_t)pixr * C + hi * 8;
    short8 a0 = *(const short8*)(fp);
    short8 a1 = *(const short8*)(fp + 32);
    short8 a2 = *(const short8*)(fp + 64);
    short8 a3 = *(const short8*)(fp + 96);

    const __hip_bfloat16* wbase = wfrag + mat * 16384 + hi * 1024 + r16 * 8;
    int orow = blockIdx.x * 64 + wid * 16 + hi * 4;

    #pragma unroll
    for (int ntl = 0; ntl < 4; ++ntl) {
        int nt = z * 4 + ntl;
        f32x4 acc = {0.f, 0.f, 0.f, 0.f};
        acc = __builtin_amdgcn_mfma_f32_16x16x32_bf16(a0, *(const short8*)(wbase + nt*128 +     0), acc, 0, 0, 0);
        acc = __builtin_amdgcn_mfma_f32_16x16x32_bf16(a1, *(const short8*)(wbase + nt*128 +  4096), acc, 0, 0, 0);
        acc = __builtin_amdgcn_mfma_f32_16x16x32_bf16(a2, *(const short8*)(wbase + nt*128 +  8192), acc, 0, 0, 0);
        acc = __builtin_amdgcn_mfma_f32_16x16x32_bf16(a3, *(const short8*)(wbase + nt*128 + 12288), acc, 0, 0, 0);
        int col  = nt * 16 + r16;
        float bb = Bv[col];
        #pragma unroll
        for (int rg = 0; rg < 4; ++rg)
            O[(size_t)(orow + rg) * C + col] = __float2bfloat16(acc[rg] + bb);
    }
}

// ---------- Kernel 3: 7x7 NAT via MFMA, 4x4 pixel tile per block -----------------------
#define VPITCH 272   // bytes per vT / attnW row (136 shorts = 17*16B)

__global__ __launch_bounds__(256) void attn_kernel(
    const __hip_bfloat16* __restrict__ qg, const __hip_bfloat16* __restrict__ kg,
    const __hip_bfloat16* __restrict__ vg, float* __restrict__ out)
{
    __shared__ __align__(16) short vT[128 * 136];       // 34816 B: vT[c][n] (swizzled)
    __shared__ __align__(16) float logit_s[16 * 116];   //  7424 B
    __shared__ __align__(16) short attnW[16 * 136];     //  4352 B: attnW[p][n]

    int t    = threadIdx.x;
    int lane = t & 63, wid = t >> 6;
    int r16  = lane & 15, hi = lane >> 4;

    int bx = blockIdx.x;                 // 4 * 196
    int b  = bx / 196;
    int rr = bx % 196;
    int th = rr / 14, tw = rr % 14;
    int ih0 = min(max(th*4 - 3, 0), HW - 10);
    int iw0 = min(max(tw*4 - 3, 0), HW - 10);

    // zero attnW (read as A-operand with K=128; cols >= window must be 0)
    {
        unsigned* aw = (unsigned*)attnW;
        for (int i = t; i < 1088; i += 256) aw[i] = 0u;
    }

    // stage vT[c][n] = v[pix(n)][c], n packed in pairs (u32), rows c & c+1 per thread.
    // phys byte within row: (4*np) ^ (hsw<<4), hsw = (c>>3)&7  (XOR bits 4-6 only)
    const unsigned* vgu = (const unsigned*)vg;
    #pragma unroll 4
    for (int it = 0; it < 16; ++it) {
        int i  = t + 256*it;        // 0..4095
        int np = i >> 6;            // 0..63  (neighbor pair, covers n 0..127)
        int c2 = i & 63;
        int n0 = min(2*np,     99);
        int n1 = min(2*np + 1, 99);
        int p0 = b*PPI + (ih0 + n0/10)*HW + (iw0 + n0%10);
        int p1 = b*PPI + (ih0 + n1/10)*HW + (iw0 + n1%10);
        unsigned av = vgu[(size_t)p0*64 + c2];
        unsigned bv = vgu[(size_t)p1*64 + c2];
        unsigned w0 = (av & 0xffffu) | (bv << 16);          // channels 2c2 of n0,n1
        unsigned w1 = (av >> 16)     | (bv & 0xffff0000u);  // channels 2c2+1
        int c    = 2*c2;
        int hsw  = (c >> 3) & 7;
        int off  = (4*np) ^ (hsw << 4);
        *(unsigned*)((char*)vT + c*VPITCH + off)          = w0;
        *(unsigned*)((char*)vT + c*VPITCH + VPITCH + off) = w1;
    }

    // Q A-fragments (row = r16 = tile pixel), direct from global
    int ph = th*4 + (r16 >> 2), pw = tw*4 + (r16 & 3);
    const short* qrow = (const short*)qg + (size_t)(b*PPI + ph*HW + pw)*C + hi*8;
    short8 qa0 = *(const short8*)(qrow);
    short8 qa1 = *(const short8*)(qrow + 32);
    short8 qa2 = *(const short8*)(qrow + 64);
    short8 qa3 = *(const short8*)(qrow + 96);

    __syncthreads();

    // QK^T: logits[16][112], N-tiles split across waves
    for (int nt = wid; nt < 7; nt += 4) {
        int n  = nt*16 + r16;
        int nc = min(n, 99);
        int kp = b*PPI + (ih0 + nc/10)*HW + (iw0 + nc%10);
        const short* krow = (const short*)kg + (size_t)kp*C + hi*8;
        f32x4 acc = {0.f, 0.f, 0.f, 0.f};
        acc = __builtin_amdgcn_mfma_f32_16x16x32_bf16(qa0, *(const short8*)(krow),      acc, 0, 0, 0);
        acc = __builtin_amdgcn_mfma_f32_16x16x32_bf16(qa1, *(const short8*)(krow + 32), acc, 0, 0, 0);
        acc = __builtin_amdgcn_mfma_f32_16x16x32_bf16(qa2, *(const short8*)(krow + 64), acc, 0, 0, 0);
        acc = __builtin_amdgcn_mfma_f32_16x16x32_bf16(qa3, *(const short8*)(krow + 96), acc, 0, 0, 0);
        #pragma unroll
        for (int rg = 0; rg < 4; ++rg)
            logit_s[(hi*4 + rg)*116 + nt*16 + r16] = acc[rg];
    }
    __syncthreads();

    // softmax per pixel (4 px per wave), scatter bf16 weights into attnW
    {
        int r7 = lane / 7, s7 = lane - 7*r7;
        bool valid = lane < 49;
        const float scale = 0.08838834764831845f;   // 128^-0.5
        #pragma unroll
        for (int px = 0; px < 4; ++px) {
            int p = wid*4 + px;
            int h = th*4 + (p >> 2), w = tw*4 + (p & 3);
            int hs = min(max(h - 3, 0), HW - 7);
            int ws = min(max(w - 3, 0), HW - 7);
            int col = (hs - ih0 + r7)*10 + (ws - iw0 + s7);
            float lg = valid ? logit_s[p*116 + col] * scale : -INFINITY;
            float m = lg;
            #pragma unroll
            for (int d = 1; d < 64; d <<= 1) m = fmaxf(m, __shfl_xor(m, d));
            float e = valid ? __expf(lg - m) : 0.f;
            float s = e;
            #pragma unroll
            for (int d = 1; d < 64; d <<= 1) s += __shfl_xor(s, d);
            if (valid) {
                __hip_bfloat16 hb = __float2bfloat16(e / s);
                *(__hip_bfloat16*)((char*)attnW + p*VPITCH + 2*col) = hb;
            }
        }
    }
    __syncthreads();

    // PV: out[16][128] = attnW[16][128] x vT^T ; A from attnW rows, B from vT rows
    short8 pa[4];
    #pragma unroll
    for (int kk = 0; kk < 4; ++kk)
        pa[kk] = *(const short8*)((char*)attnW + r16*VPITCH + kk*64 + hi*16);

    for (int nt = wid; nt < 8; nt += 4) {
        int c   = nt*16 + r16;
        int hsw = (c >> 3) & 7;
        const char* vrow = (const char*)vT + c*VPITCH;
        f32x4 acc = {0.f, 0.f, 0.f, 0.f};
        #pragma unroll
        for (int kk = 0; kk < 4; ++kk) {
            short8 vb = *(const short8*)(vrow + ((kk*64 + hi*16) ^ (hsw << 4)));
            acc = __builtin_amdgcn_mfma_f32_16x16x32_bf16(pa[kk], vb, acc, 0, 0, 0);
        }
        #pragma unroll
        for (int rg = 0; rg < 4; ++rg) {
            int p = hi*4 + rg;
            int h = th*4 + (p >> 2), w = tw*4 + (p & 3);
            out[(((size_t)b*C + c)*HW + h)*HW + w] = acc[rg];
        }
    }
}

extern "C" void kernel_launch(void* const* d_in, const int* in_sizes, int n_in,
                              void* d_out, int out_size, void* d_ws, size_t ws_size,
                              hipStream_t stream) {
    const float* x      = (const float*)d_in[0];
    const float* conv_w = (const float*)d_in[1];
    const float* conv_b = (const float*)d_in[2];
    const float* q_w    = (const float*)d_in[3];
    const float* q_b    = (const float*)d_in[4];
    const float* k_w    = (const float*)d_in[5];
    const float* k_b    = (const float*)d_in[6];
    const float* v_w    = (const float*)d_in[7];
    const float* v_b    = (const float*)d_in[8];
    float* out = (float*)d_out;

    __hip_bfloat16* f_bf  = (__hip_bfloat16*)d_ws;       // NPIX*C
    __hip_bfloat16* q_bf  = f_bf + (size_t)NPIX * C;
    __hip_bfloat16* k_bf  = q_bf + (size_t)NPIX * C;
    __hip_bfloat16* v_bf  = k_bf + (size_t)NPIX * C;
    __hip_bfloat16* wfrag = v_bf + (size_t)NPIX * C;     // 3*16384

    conv_wprep_kernel<<<CONV_BLOCKS2 + WPREP_BLOCKS, 256, 0, stream>>>(
        x, conv_w, conv_b, q_w, k_w, v_w, f_bf, wfrag);
    qkv_mfma_kernel<<<dim3(NPIX/64, 3, 2), 256, 0, stream>>>(
        f_bf, wfrag, q_b, k_b, v_b, q_bf, k_bf, v_bf);
    attn_kernel<<<NB*14*14, 256, 0, stream>>>(q_bf, k_bf, v_bf, out);
}

// Round 5
// 44.439 us; speedup vs baseline: 3.4036x; 1.2551x over previous
//
#include <hip/hip_runtime.h>
#include <hip/hip_bf16.h>
#include <math.h>

#define HW 56
#define PPI (HW*HW)          // 3136 pixels per image
#define NB 4
#define C 128
#define NPIX (NB*PPI)        // 12544

typedef __attribute__((ext_vector_type(8))) short short8;
typedef __attribute__((ext_vector_type(4))) float f32x4;

__device__ __forceinline__ short bfbits(float v) {
    __hip_bfloat16 hb = __float2bfloat16(v);
    return *reinterpret_cast<short*>(&hb);
}

// ---------- Kernel 1: weight prep (qkv B-frags + conv B-frags) -------------------------
// wqkv[m][(kk*4+hi)*128 + col)*8 + j] = bf16(W_m[col][k]), k = kk*32+hi*8+j
// wcf[(hi*128 + cout)*8 + j]          = bf16(conv_w[cout][k]) for k=hi*8+j<27 else 0
__global__ __launch_bounds__(256) void prep_kernel(
    const float* __restrict__ cw,
    const float* __restrict__ qw, const float* __restrict__ kw,
    const float* __restrict__ vw,
    __hip_bfloat16* __restrict__ wcf, __hip_bfloat16* __restrict__ wqkv)
{
    int gid = blockIdx.x * 256 + threadIdx.x;
    if (blockIdx.x < 192) {
        int m   = gid >> 14;
        int r   = gid & 16383;
        int col = r >> 7;
        int k   = r & 127;
        const float* W = (m == 0) ? qw : (m == 1) ? kw : vw;
        int kk = k >> 5, hi = (k >> 3) & 3, j = k & 7;
        wqkv[m * 16384 + ((kk * 4 + hi) * 128 + col) * 8 + j] = __float2bfloat16(W[col * 128 + k]);
    } else {
        int idx = gid - 192 * 256;          // 0..4095
        int hi = idx >> 10, cout = (idx >> 3) & 127, j = idx & 7;
        int k  = hi * 8 + j;
        float v = (k < 27) ? cw[cout * 27 + k] : 0.f;
        wcf[(hi * 128 + cout) * 8 + j] = __float2bfloat16(v);
    }
}

// ---------- Kernel 2: fused conv3x3s2(relu) + QKV GEMM, all MFMA -----------------------
// 784 blocks (4x4 pixel tile each), 256 threads = 4 waves.
// Phase A: implicit-GEMM conv (K=27 pad 32) -> f tile [16px][128] in LDS (bf16, swizzled)
// Phase B: q/k/v = f @ W^T + b, 24 (mat,nt) tiles over 4 waves.
__global__ __launch_bounds__(256) void convqkv_kernel(
    const float* __restrict__ x, const __hip_bfloat16* __restrict__ wcf,
    const float* __restrict__ cb, const __hip_bfloat16* __restrict__ wqkv,
    const float* __restrict__ qb, const float* __restrict__ kb,
    const float* __restrict__ vb,
    __hip_bfloat16* __restrict__ qo, __hip_bfloat16* __restrict__ ko,
    __hip_bfloat16* __restrict__ vo)
{
    __shared__ __align__(16) short f_lds[16 * 128];   // 4 KB, XOR-swizzled

    int t = threadIdx.x, lane = t & 63, wid = t >> 6;
    int r16 = lane & 15, hi = lane >> 4;

    int bx = blockIdx.x;                 // 4 * 196
    int bimg = bx / 196;
    int rr = bx % 196;
    int th = rr / 14, tw = rr % 14;

    // ---- Phase A: im2col A-fragment (row = r16 = tile pixel, k = hi*8+j) ----
    int h = th * 4 + (r16 >> 2), w = tw * 4 + (r16 & 3);
    short8 af;
    #pragma unroll
    for (int j = 0; j < 8; ++j) {
        int k = hi * 8 + j;
        float xv = 0.f;
        if (k < 27) {
            int ci = k / 9, r9 = k % 9;
            int kh = r9 / 3, kw_ = r9 % 3;
            int ih = 2 * h - 1 + kh, iw = 2 * w - 1 + kw_;
            if (ih >= 0 && ih < 112 && iw >= 0 && iw < 112)
                xv = x[((size_t)(bimg * 3 + ci) * 112 + ih) * 112 + iw];
        }
        af[j] = bfbits(xv);
    }

    #pragma unroll
    for (int ctl = 0; ctl < 2; ++ctl) {
        int ct = wid * 2 + ctl;                       // col-tile 0..7
        int cout = ct * 16 + r16;
        short8 bw = *(const short8*)((const short*)wcf + (hi * 128 + cout) * 8);
        f32x4 acc = {0.f, 0.f, 0.f, 0.f};
        acc = __builtin_amdgcn_mfma_f32_16x16x32_bf16(af, bw, acc, 0, 0, 0);
        float bias = cb[cout];
        int colblk = cout >> 3, inb = (cout & 7) * 2;
        #pragma unroll
        for (int rg = 0; rg < 4; ++rg) {
            int px = hi * 4 + rg;
            float v = fmaxf(acc[rg] + bias, 0.f);
            *(short*)((char*)f_lds + px * 256 + ((colblk ^ px) << 4) + inb) = bfbits(v);
        }
    }
    __syncthreads();

    // ---- Phase B: A-frags from f_lds (row = r16, k = kk*32+hi*8) ----
    short8 fa[4];
    #pragma unroll
    for (int kk = 0; kk < 4; ++kk) {
        int colblk = kk * 4 + hi;
        fa[kk] = *(const short8*)((char*)f_lds + r16 * 256 + ((colblk ^ r16) << 4));
    }

    #pragma unroll
    for (int i = 0; i < 6; ++i) {
        int idx = wid * 6 + i;                        // 0..23
        int mat = idx >> 3, nt = idx & 7;
        const short* wb = (const short*)wqkv + mat * 16384 + hi * 1024 + r16 * 8 + nt * 128;
        f32x4 acc = {0.f, 0.f, 0.f, 0.f};
        acc = __builtin_amdgcn_mfma_f32_16x16x32_bf16(fa[0], *(const short8*)(wb),         acc, 0, 0, 0);
        acc = __builtin_amdgcn_mfma_f32_16x16x32_bf16(fa[1], *(const short8*)(wb +  4096), acc, 0, 0, 0);
        acc = __builtin_amdgcn_mfma_f32_16x16x32_bf16(fa[2], *(const short8*)(wb +  8192), acc, 0, 0, 0);
        acc = __builtin_amdgcn_mfma_f32_16x16x32_bf16(fa[3], *(const short8*)(wb + 12288), acc, 0, 0, 0);
        int col = nt * 16 + r16;
        const float* Bv   = (mat == 0) ? qb : (mat == 1) ? kb : vb;
        __hip_bfloat16* O = (mat == 0) ? qo : (mat == 1) ? ko : vo;
        float bb = Bv[col];
        #pragma unroll
        for (int rg = 0; rg < 4; ++rg) {
            int px = hi * 4 + rg;
            int hh = th * 4 + (px >> 2), ww = tw * 4 + (px & 3);
            O[((size_t)(bimg * PPI + hh * HW + ww)) * C + col] = __float2bfloat16(acc[rg] + bb);
        }
    }
}

// ---------- Kernel 3: 7x7 NAT via MFMA, 4x4 pixel tile per block -----------------------
#define VPITCH 272   // bytes per vT / attnW row (136 shorts = 17*16B)

__global__ __launch_bounds__(256) void attn_kernel(
    const __hip_bfloat16* __restrict__ qg, const __hip_bfloat16* __restrict__ kg,
    const __hip_bfloat16* __restrict__ vg, float* __restrict__ out)
{
    __shared__ __align__(16) short vT[128 * 136];       // 34816 B: vT[c][n] (swizzled)
    __shared__ __align__(16) float logit_s[16 * 116];   //  7424 B
    __shared__ __align__(16) short attnW[16 * 136];     //  4352 B: attnW[p][n]

    int t    = threadIdx.x;
    int lane = t & 63, wid = t >> 6;
    int r16  = lane & 15, hi = lane >> 4;

    int bx = blockIdx.x;                 // 4 * 196
    int b  = bx / 196;
    int rr = bx % 196;
    int th = rr / 14, tw = rr % 14;
    int ih0 = min(max(th*4 - 3, 0), HW - 10);
    int iw0 = min(max(tw*4 - 3, 0), HW - 10);

    // zero attnW (read as A-operand with K=128; cols >= window must be 0)
    {
        unsigned* aw = (unsigned*)attnW;
        for (int i = t; i < 1088; i += 256) aw[i] = 0u;
    }

    // stage vT[c][n] = v[pix(n)][c], n packed in pairs (u32), rows c & c+1 per thread.
    const unsigned* vgu = (const unsigned*)vg;
    #pragma unroll 4
    for (int it = 0; it < 16; ++it) {
        int i  = t + 256*it;        // 0..4095
        int np = i >> 6;            // 0..63
        int c2 = i & 63;
        int n0 = min(2*np,     99);
        int n1 = min(2*np + 1, 99);
        int p0 = b*PPI + (ih0 + n0/10)*HW + (iw0 + n0%10);
        int p1 = b*PPI + (ih0 + n1/10)*HW + (iw0 + n1%10);
        unsigned av = vgu[(size_t)p0*64 + c2];
        unsigned bv = vgu[(size_t)p1*64 + c2];
        unsigned w0 = (av & 0xffffu) | (bv << 16);
        unsigned w1 = (av >> 16)     | (bv & 0xffff0000u);
        int c    = 2*c2;
        int hsw  = (c >> 3) & 7;
        int off  = (4*np) ^ (hsw << 4);
        *(unsigned*)((char*)vT + c*VPITCH + off)          = w0;
        *(unsigned*)((char*)vT + c*VPITCH + VPITCH + off) = w1;
    }

    // Q A-fragments (row = r16 = tile pixel), direct from global
    int ph = th*4 + (r16 >> 2), pw = tw*4 + (r16 & 3);
    const short* qrow = (const short*)qg + (size_t)(b*PPI + ph*HW + pw)*C + hi*8;
    short8 qa0 = *(const short8*)(qrow);
    short8 qa1 = *(const short8*)(qrow + 32);
    short8 qa2 = *(const short8*)(qrow + 64);
    short8 qa3 = *(const short8*)(qrow + 96);

    __syncthreads();

    // QK^T: logits[16][112], N-tiles split across waves
    for (int nt = wid; nt < 7; nt += 4) {
        int n  = nt*16 + r16;
        int nc = min(n, 99);
        int kp = b*PPI + (ih0 + nc/10)*HW + (iw0 + nc%10);
        const short* krow = (const short*)kg + (size_t)kp*C + hi*8;
        f32x4 acc = {0.f, 0.f, 0.f, 0.f};
        acc = __builtin_amdgcn_mfma_f32_16x16x32_bf16(qa0, *(const short8*)(krow),      acc, 0, 0, 0);
        acc = __builtin_amdgcn_mfma_f32_16x16x32_bf16(qa1, *(const short8*)(krow + 32), acc, 0, 0, 0);
        acc = __builtin_amdgcn_mfma_f32_16x16x32_bf16(qa2, *(const short8*)(krow + 64), acc, 0, 0, 0);
        acc = __builtin_amdgcn_mfma_f32_16x16x32_bf16(qa3, *(const short8*)(krow + 96), acc, 0, 0, 0);
        #pragma unroll
        for (int rg = 0; rg < 4; ++rg)
            logit_s[(hi*4 + rg)*116 + nt*16 + r16] = acc[rg];
    }
    __syncthreads();

    // softmax per pixel (4 px per wave), scatter bf16 weights into attnW
    {
        int r7 = lane / 7, s7 = lane - 7*r7;
        bool valid = lane < 49;
        const float scale = 0.08838834764831845f;   // 128^-0.5
        #pragma unroll
        for (int px = 0; px < 4; ++px) {
            int p = wid*4 + px;
            int h = th*4 + (p >> 2), w = tw*4 + (p & 3);
            int hs = min(max(h - 3, 0), HW - 7);
            int ws = min(max(w - 3, 0), HW - 7);
            int col = (hs - ih0 + r7)*10 + (ws - iw0 + s7);
            float lg = valid ? logit_s[p*116 + col] * scale : -INFINITY;
            float m = lg;
            #pragma unroll
            for (int d = 1; d < 64; d <<= 1) m = fmaxf(m, __shfl_xor(m, d));
            float e = valid ? __expf(lg - m) : 0.f;
            float s = e;
            #pragma unroll
            for (int d = 1; d < 64; d <<= 1) s += __shfl_xor(s, d);
            if (valid) {
                __hip_bfloat16 hb = __float2bfloat16(e / s);
                *(__hip_bfloat16*)((char*)attnW + p*VPITCH + 2*col) = hb;
            }
        }
    }
    __syncthreads();

    // PV: out[16][128] = attnW[16][128] x vT^T
    short8 pa[4];
    #pragma unroll
    for (int kk = 0; kk < 4; ++kk)
        pa[kk] = *(const short8*)((char*)attnW + r16*VPITCH + kk*64 + hi*16);

    for (int nt = wid; nt < 8; nt += 4) {
        int c   = nt*16 + r16;
        int hsw = (c >> 3) & 7;
        const char* vrow = (const char*)vT + c*VPITCH;
        f32x4 acc = {0.f, 0.f, 0.f, 0.f};
        #pragma unroll
        for (int kk = 0; kk < 4; ++kk) {
            short8 vb = *(const short8*)(vrow + ((kk*64 + hi*16) ^ (hsw << 4)));
            acc = __builtin_amdgcn_mfma_f32_16x16x32_bf16(pa[kk], vb, acc, 0, 0, 0);
        }
        #pragma unroll
        for (int rg = 0; rg < 4; ++rg) {
            int p = hi*4 + rg;
            int h = th*4 + (p >> 2), w = tw*4 + (p & 3);
            out[(((size_t)b*C + c)*HW + h)*HW + w] = acc[rg];
        }
    }
}

extern "C" void kernel_launch(void* const* d_in, const int* in_sizes, int n_in,
                              void* d_out, int out_size, void* d_ws, size_t ws_size,
                              hipStream_t stream) {
    const float* x      = (const float*)d_in[0];
    const float* conv_w = (const float*)d_in[1];
    const float* conv_b = (const float*)d_in[2];
    const float* q_w    = (const float*)d_in[3];
    const float* q_b    = (const float*)d_in[4];
    const float* k_w    = (const float*)d_in[5];
    const float* k_b    = (const float*)d_in[6];
    const float* v_w    = (const float*)d_in[7];
    const float* v_b    = (const float*)d_in[8];
    float* out = (float*)d_out;

    __hip_bfloat16* q_bf  = (__hip_bfloat16*)d_ws;       // NPIX*C
    __hip_bfloat16* k_bf  = q_bf + (size_t)NPIX * C;
    __hip_bfloat16* v_bf  = k_bf + (size_t)NPIX * C;
    __hip_bfloat16* wqkv  = v_bf + (size_t)NPIX * C;     // 3*16384
    __hip_bfloat16* wcf   = wqkv + 3 * 16384;            // 4096

    prep_kernel<<<208, 256, 0, stream>>>(conv_w, q_w, k_w, v_w, wcf, wqkv);
    convqkv_kernel<<<NB*196, 256, 0, stream>>>(x, wcf, conv_b, wqkv,
                                               q_b, k_b, v_b, q_bf, k_bf, v_bf);
    attn_kernel<<<NB*196, 256, 0, stream>>>(q_bf, k_bf, v_bf, out);
}